// Round 1
// baseline (335.341 us; speedup 1.0000x reference)
//
#include <hip/hip_runtime.h>

#define ALPHA 0.2f

typedef __attribute__((ext_vector_type(8))) short short8;
typedef __attribute__((ext_vector_type(4))) float f32x4;

// ---------- helpers ----------
__device__ __forceinline__ unsigned short f2b(float f) {
  // round-to-nearest-even f32 -> bf16 bits
  unsigned int u; __builtin_memcpy(&u, &f, 4);
  unsigned int r = (u + 0x7FFFu + ((u >> 16) & 1u)) >> 16;
  return (unsigned short)r;
}
__device__ __forceinline__ float b2f(unsigned short v) {
  unsigned int u = ((unsigned int)v) << 16; float f; __builtin_memcpy(&f, &u, 4); return f;
}
__device__ __forceinline__ void gl_lds16(const unsigned short* g, unsigned short* l) {
  // async global->LDS, 16B/lane; LDS dst = wave-uniform base + lane*16
  __builtin_amdgcn_global_load_lds((__attribute__((address_space(1))) void*)g,
                                   (__attribute__((address_space(3))) void*)l, 16, 0, 0);
}

// ---------- prep kernels ----------
// adj (int 0/1) -> bitmask, 1 bit per edge. 64MB read once; later passes read 2MB.
__global__ __launch_bounds__(256) void pack_adj(const int* __restrict__ adj,
                                                unsigned long long* __restrict__ bm) {
  unsigned int id = blockIdx.x * 256 + threadIdx.x;
  unsigned long long m = __ballot(adj[id] > 0);
  if ((threadIdx.x & 63) == 0) bm[id >> 6] = m;
}

// fp32 -> bf16, 4 elems/thread
__global__ __launch_bounds__(256) void cvt_f32_bf16(const float* __restrict__ in,
                                                    unsigned short* __restrict__ out) {
  unsigned int id = blockIdx.x * 256 + threadIdx.x;
  float4 v = ((const float4*)in)[id];
  alignas(8) unsigned short o[4];
  o[0] = f2b(v.x); o[1] = f2b(v.y); o[2] = f2b(v.z); o[3] = f2b(v.w);
  ((uint2*)out)[id] = *(const uint2*)o;
}

// W (1024x512) -> Wt bf16 (512x1024): coalesced writes, reads served by L2 (W=2MB)
__global__ __launch_bounds__(256) void transpose_W(const float* __restrict__ W,
                                                   unsigned short* __restrict__ Wt) {
  unsigned int id = blockIdx.x * 256 + threadIdx.x;   // 524288
  unsigned int k = id & 1023, n = id >> 10;
  Wt[id] = f2b(W[k * 512 + n]);
}

// f1[m]=h[m]·a1, f2[m]=h[m]·a2 ; one wave per row, b128 loads + shuffle reduce
__global__ __launch_bounds__(256) void f1f2_kernel(const unsigned short* __restrict__ hp,
                                                   const float* __restrict__ a,
                                                   float* __restrict__ f1, float* __restrict__ f2) {
  int row = blockIdx.x * 4 + (threadIdx.x >> 6);
  int lane = threadIdx.x & 63;
  const unsigned short* hrow = hp + (size_t)row * 1024 + 512;
  uint4 raw = *(const uint4*)(hrow + lane * 8);
  alignas(16) unsigned short hv[8]; __builtin_memcpy(hv, &raw, 16);
  float s1 = 0.f, s2 = 0.f;
  #pragma unroll
  for (int j = 0; j < 8; j++) {
    float hf = b2f(hv[j]);
    s1 += hf * a[lane * 8 + j];
    s2 += hf * a[512 + lane * 8 + j];
  }
  #pragma unroll
  for (int o = 32; o > 0; o >>= 1) { s1 += __shfl_down(s1, o); s2 += __shfl_down(s2, o); }
  if (lane == 0) { f1[row] = s1; f2[row] = s2; }
}

// hp h-half -> ht[b][f][i] (B^T layout for attention GEMM), 64x64 LDS tile transpose
__global__ __launch_bounds__(256) void transpose_h(const unsigned short* __restrict__ hp,
                                                   unsigned short* __restrict__ ht) {
  __shared__ alignas(16) unsigned short tile[64][72];
  int b = blockIdx.z, i0 = blockIdx.x * 64, f0 = blockIdx.y * 64;
  int tid = threadIdx.x;
  #pragma unroll
  for (int p = 0; p < 2; p++) {
    int r = p * 32 + (tid >> 3);
    int c = (tid & 7) * 8;
    uint4 v = *(const uint4*)(hp + (size_t)(b * 1024 + i0 + r) * 1024 + 512 + f0 + c);
    *(uint4*)(&tile[r][c]) = v;
  }
  __syncthreads();
  int f = tid >> 2;
  int ic = (tid & 3) * 16;
  alignas(16) unsigned short buf[16];
  #pragma unroll
  for (int k = 0; k < 16; k++) buf[k] = tile[ic + k][f];
  uint4* dst = (uint4*)(ht + (size_t)(b * 512 + f0 + f) * 1024 + i0 + ic);
  dst[0] = ((const uint4*)buf)[0];
  dst[1] = ((const uint4*)buf)[1];
}

// inv_l[row] = 1 / sum_j mask * exp(lrelu(f1+f2))  (no max-subtraction: |e| small)
__global__ __launch_bounds__(256) void rowsum(const unsigned long long* __restrict__ bm,
                                              const float* __restrict__ f1,
                                              const float* __restrict__ f2,
                                              float* __restrict__ invl) {
  int row = blockIdx.x * 4 + (threadIdx.x >> 6);
  int lane = threadIdx.x & 63;
  int b = row >> 10;
  float f1v = f1[row];
  const float* f2b_ = f2 + (b << 10);
  float s = 0.f;
  #pragma unroll
  for (int it = 0; it < 16; it++) {
    unsigned long long w = bm[(size_t)row * 16 + it];
    if ((w >> lane) & 1ull) {
      float z = f1v + f2b_[it * 64 + lane];
      z = z > 0.f ? z : ALPHA * z;
      s += __expf(z);
    }
  }
  #pragma unroll
  for (int o = 32; o > 0; o >>= 1) s += __shfl_down(s, o);
  if (lane == 0) invl[row] = 1.0f / s;
}

// unnormalized P~ = mask * exp(lrelu(f1+f2)) in bf16, 8 j's per thread
__global__ __launch_bounds__(256) void compute_P(const unsigned char* __restrict__ bm8,
                                                 const float* __restrict__ f1,
                                                 const float* __restrict__ f2,
                                                 unsigned short* __restrict__ P) {
  unsigned int id = blockIdx.x * 256 + threadIdx.x;  // 2,097,152
  unsigned int j8 = id & 127;
  unsigned int bi = id >> 7;
  unsigned int b = bi >> 10;
  unsigned int bits = bm8[id];
  float f1v = f1[bi];
  const float* f2p = f2 + (b << 10) + j8 * 8;
  alignas(16) unsigned short o[8];
  #pragma unroll
  for (int jj = 0; jj < 8; jj++) {
    float p = 0.f;
    if ((bits >> jj) & 1u) {
      float z = f1v + f2p[jj];
      z = z > 0.f ? z : ALPHA * z;
      p = __expf(z);
    }
    o[jj] = f2b(p);
  }
  *(uint4*)(P + (size_t)id * 8) = *(const uint4*)o;
}

// ---------- bf16 GEMM: C(MxN) = A(MxK) @ Bt(NxK)^T, m97 structure ----------
// 128x128 tile, BK=32, 4 waves each 64x64 (4x4 of 16x16x32 MFMA), global_load_lds w16.
// EPI 1: bf16 out at [m][ocol+n]   (h -> hp right half)
// EPI 2: fp32 out, +bias, ELU      (final output)
// EPI 3: bf16 out, * scale[row]    (agg -> hp left half, scale = 1/l)
template <int EPI>
__global__ __launch_bounds__(256) void gemm_bt(
    const unsigned short* __restrict__ A, size_t aBS,
    const unsigned short* __restrict__ Bt, size_t bBS,
    int K,
    void* __restrict__ outp, size_t oBS, int ldo, int ocol,
    const float* __restrict__ scale,
    const float* __restrict__ bias) {
  __shared__ alignas(16) unsigned short As[128 * 32];
  __shared__ alignas(16) unsigned short Bs[128 * 32];
  const int tid = threadIdx.x;
  const int lane = tid & 63;
  const int w = tid >> 6;
  const int m0 = blockIdx.x * 128;
  const int n0 = blockIdx.y * 128;
  const int zb = blockIdx.z;
  const unsigned short* Ab = A + (size_t)zb * aBS;
  const unsigned short* Btb = Bt + (size_t)zb * bBS;

  f32x4 acc[4][4];
  #pragma unroll
  for (int i = 0; i < 4; i++)
    #pragma unroll
    for (int j = 0; j < 4; j++)
      #pragma unroll
      for (int r = 0; r < 4; r++) acc[i][j][r] = 0.f;

  // staging: per wave 2 instrs/operand; lane L -> row L/4, col 8*(L%4)
  const int sr = w * 32 + (lane >> 2);
  const int sc = (lane & 3) * 8;
  const unsigned short* ag = Ab + (size_t)(m0 + sr) * K + sc;
  const unsigned short* bg = Btb + (size_t)(n0 + sr) * K + sc;
  unsigned short* asl = As + w * 1024;
  unsigned short* bsl = Bs + w * 1024;

  const int wm = (w & 1) * 64;
  const int wn = (w >> 1) * 64;
  const int row16 = lane & 15;
  const int quad = lane >> 4;

  for (int k0 = 0; k0 < K; k0 += 32) {
    __syncthreads();
    gl_lds16(ag + k0, asl);
    gl_lds16(ag + k0 + (size_t)16 * K, asl + 512);
    gl_lds16(bg + k0, bsl);
    gl_lds16(bg + k0 + (size_t)16 * K, bsl + 512);
    __syncthreads();
    short8 af[4], bf[4];
    #pragma unroll
    for (int am = 0; am < 4; am++)
      af[am] = *(const short8*)(As + (wm + am * 16 + row16) * 32 + quad * 8);
    #pragma unroll
    for (int bn = 0; bn < 4; bn++)
      bf[bn] = *(const short8*)(Bs + (wn + bn * 16 + row16) * 32 + quad * 8);
    #pragma unroll
    for (int am = 0; am < 4; am++)
      #pragma unroll
      for (int bn = 0; bn < 4; bn++)
        acc[am][bn] = __builtin_amdgcn_mfma_f32_16x16x32_bf16(af[am], bf[bn], acc[am][bn], 0, 0, 0);
  }

  // C/D layout: col = lane&15, row = (lane>>4)*4 + reg  [m89/m91-verified]
  const int col = lane & 15;
  const int r0 = quad * 4;
  #pragma unroll
  for (int am = 0; am < 4; am++) {
    #pragma unroll
    for (int bn = 0; bn < 4; bn++) {
      #pragma unroll
      for (int r = 0; r < 4; r++) {
        int m = m0 + wm + am * 16 + r0 + r;
        int n = n0 + wn + bn * 16 + col;
        float v = acc[am][bn][r];
        if (EPI == 3) v *= scale[zb * 1024 + m];
        if (EPI == 2) {
          v += bias[n];
          v = v > 0.f ? v : expm1f(v);   // ELU, alpha=1
          ((float*)outp)[(size_t)m * ldo + n] = v;
        } else {
          ((unsigned short*)outp)[(size_t)zb * oBS + (size_t)m * ldo + ocol + n] = f2b(v);
        }
      }
    }
  }
}

// ---------- launch ----------
extern "C" void kernel_launch(void* const* d_in, const int* in_sizes, int n_in,
                              void* d_out, int out_size, void* d_ws, size_t ws_size,
                              hipStream_t stream) {
  const float* x   = (const float*)d_in[0];  // (16,1024,1024)
  const int*   adj = (const int*)d_in[1];    // (16,1024,1024)
  const float* W   = (const float*)d_in[2];  // (1024,512)
  const float* a   = (const float*)d_in[3];  // (1024,1)
  const float* fcw = (const float*)d_in[4];  // (512,1024)  == Bt layout for GEMM3
  const float* fcb = (const float*)d_in[5];  // (512,)
  float* out = (float*)d_out;                // (16,1024,512) fp32
  char* ws = (char*)d_ws;

  // ws layout (84.2 MiB total; xb slot reused for P after GEMM1 consumes x)
  unsigned short* xb   = (unsigned short*)(ws);               // 32MB x_bf16 -> later P~
  unsigned short* hp   = (unsigned short*)(ws + 33554432);    // 32MB [agg | h] bf16 rows
  unsigned short* ht   = (unsigned short*)(ws + 67108864);    // 16MB h^T per batch
  unsigned short* Wt   = (unsigned short*)(ws + 83886080);    // 1MB
  unsigned short* fcwb = (unsigned short*)(ws + 84934656);    // 1MB
  float* f1            = (float*)(ws + 85983232);             // 64KB
  float* f2            = (float*)(ws + 86048768);             // 64KB
  float* invl          = (float*)(ws + 86114304);             // 64KB
  unsigned long long* bm = (unsigned long long*)(ws + 86179840); // 2MB
  unsigned short* P = xb;

  pack_adj<<<65536, 256, 0, stream>>>(adj, bm);
  cvt_f32_bf16<<<16384, 256, 0, stream>>>(x, xb);
  cvt_f32_bf16<<<512, 256, 0, stream>>>(fcw, fcwb);
  transpose_W<<<2048, 256, 0, stream>>>(W, Wt);

  // GEMM1: h = x @ W  -> hp[:,512:1024]
  gemm_bt<1><<<dim3(128, 4, 1), 256, 0, stream>>>(xb, 0, Wt, 0, 1024,
                                                  hp, 0, 1024, 512, nullptr, nullptr);
  f1f2_kernel<<<4096, 256, 0, stream>>>(hp, a, f1, f2);
  transpose_h<<<dim3(16, 8, 16), 256, 0, stream>>>(hp, ht);
  rowsum<<<4096, 256, 0, stream>>>(bm, f1, f2, invl);
  compute_P<<<8192, 256, 0, stream>>>((const unsigned char*)bm, f1, f2, P);

  // GEMM2 (per batch): agg = (P~/l) @ h  -> hp[:,0:512]
  gemm_bt<3><<<dim3(8, 4, 16), 256, 0, stream>>>(P, 1024 * 1024, ht, 512 * 1024, 1024,
                                                 hp, 1024 * 1024, 1024, 0, invl, nullptr);
  // GEMM3: out = elu([agg|h] @ fc_w^T + b)
  gemm_bt<2><<<dim3(128, 4, 1), 256, 0, stream>>>(hp, 0, fcwb, 0, 1024,
                                                  out, 0, 512, 0, nullptr, fcb);
}

// Round 2
// 276.232 us; speedup vs baseline: 1.2140x; 1.2140x over previous
//
#include <hip/hip_runtime.h>

#define ALPHA 0.2f

typedef __attribute__((ext_vector_type(8))) short short8;
typedef __attribute__((ext_vector_type(4))) float f32x4;

// ---------- helpers ----------
__device__ __forceinline__ unsigned short f2b(float f) {
  // round-to-nearest-even f32 -> bf16 bits
  unsigned int u; __builtin_memcpy(&u, &f, 4);
  unsigned int r = (u + 0x7FFFu + ((u >> 16) & 1u)) >> 16;
  return (unsigned short)r;
}
__device__ __forceinline__ float b2f(unsigned short v) {
  unsigned int u = ((unsigned int)v) << 16; float f; __builtin_memcpy(&f, &u, 4); return f;
}
__device__ __forceinline__ void gl_lds16(const unsigned short* g, unsigned short* l) {
  // async global->LDS, 16B/lane; LDS dst = wave-uniform base + lane*16
  __builtin_amdgcn_global_load_lds((__attribute__((address_space(1))) void*)g,
                                   (__attribute__((address_space(3))) void*)l, 16, 0, 0);
}

// ---------- prep1: pack_adj + cvt x->bf16 + cvt fcw->bf16 + transpose W ----------
// regions by blockIdx.x (wave-uniform branch):
//   [0,65536)      pack adj (16M int -> 2MB bitmask)
//   [65536,81920)  x fp32 -> bf16 (16M elems, 4/thread)
//   [81920,82432)  fcw fp32 -> bf16 (512K elems, 4/thread)
//   [82432,84480)  W (1024x512) -> Wt bf16 (512x1024); W is 2MB -> L2-resident
__global__ __launch_bounds__(256) void prep1(const int* __restrict__ adj,
                                             unsigned long long* __restrict__ bm,
                                             const float* __restrict__ x,
                                             unsigned short* __restrict__ xb,
                                             const float* __restrict__ fcw,
                                             unsigned short* __restrict__ fcwb,
                                             const float* __restrict__ W,
                                             unsigned short* __restrict__ Wt) {
  unsigned int bx = blockIdx.x;
  if (bx < 65536u) {
    unsigned int id = bx * 256 + threadIdx.x;
    unsigned long long m = __ballot(adj[id] > 0);
    if ((threadIdx.x & 63) == 0) bm[id >> 6] = m;
  } else if (bx < 81920u) {
    unsigned int id = (bx - 65536u) * 256 + threadIdx.x;
    float4 v = ((const float4*)x)[id];
    alignas(8) unsigned short o[4];
    o[0] = f2b(v.x); o[1] = f2b(v.y); o[2] = f2b(v.z); o[3] = f2b(v.w);
    ((uint2*)xb)[id] = *(const uint2*)o;
  } else if (bx < 82432u) {
    unsigned int id = (bx - 81920u) * 256 + threadIdx.x;
    float4 v = ((const float4*)fcw)[id];
    alignas(8) unsigned short o[4];
    o[0] = f2b(v.x); o[1] = f2b(v.y); o[2] = f2b(v.z); o[3] = f2b(v.w);
    ((uint2*)fcwb)[id] = *(const uint2*)o;
  } else {
    unsigned int id = (bx - 82432u) * 256 + threadIdx.x;   // 524288
    unsigned int k = id & 1023, n = id >> 10;
    Wt[id] = f2b(W[k * 512 + n]);
  }
}

// ---------- prep2: f1f2 + transpose_h (both depend only on GEMM1) ----------
__global__ __launch_bounds__(256) void prep2(const unsigned short* __restrict__ hp,
                                             const float* __restrict__ a,
                                             float* __restrict__ f1, float* __restrict__ f2,
                                             unsigned short* __restrict__ ht) {
  __shared__ alignas(16) unsigned short tile[64][72];
  int bx = blockIdx.x;
  int tid = threadIdx.x;
  if (bx < 4096) {
    // f1[m]=h[m]·a1, f2[m]=h[m]·a2 ; one wave per row
    int row = bx * 4 + (tid >> 6);
    int lane = tid & 63;
    const unsigned short* hrow = hp + (size_t)row * 1024 + 512;
    uint4 raw = *(const uint4*)(hrow + lane * 8);
    alignas(16) unsigned short hv[8]; __builtin_memcpy(hv, &raw, 16);
    float s1 = 0.f, s2 = 0.f;
    #pragma unroll
    for (int j = 0; j < 8; j++) {
      float hf = b2f(hv[j]);
      s1 += hf * a[lane * 8 + j];
      s2 += hf * a[512 + lane * 8 + j];
    }
    #pragma unroll
    for (int o = 32; o > 0; o >>= 1) { s1 += __shfl_down(s1, o); s2 += __shfl_down(s2, o); }
    if (lane == 0) { f1[row] = s1; f2[row] = s2; }
  } else {
    // hp h-half -> ht[b][f][i] (B^T layout for attention GEMM), 64x64 LDS tile transpose
    int idx = bx - 4096;                 // 2048 blocks: (16 i0) x (8 f0) x (16 b)
    int b = idx >> 7;
    int f0 = ((idx >> 4) & 7) * 64;
    int i0 = (idx & 15) * 64;
    #pragma unroll
    for (int p = 0; p < 2; p++) {
      int r = p * 32 + (tid >> 3);
      int c = (tid & 7) * 8;
      uint4 v = *(const uint4*)(hp + (size_t)(b * 1024 + i0 + r) * 1024 + 512 + f0 + c);
      *(uint4*)(&tile[r][c]) = v;
    }
    __syncthreads();
    int f = tid >> 2;
    int ic = (tid & 3) * 16;
    alignas(16) unsigned short buf[16];
    #pragma unroll
    for (int k = 0; k < 16; k++) buf[k] = tile[ic + k][f];
    uint4* dst = (uint4*)(ht + (size_t)(b * 512 + f0 + f) * 1024 + i0 + ic);
    dst[0] = ((const uint4*)buf)[0];
    dst[1] = ((const uint4*)buf)[1];
  }
}

// ---------- rowsum + P in one pass: P~ = mask*exp(lrelu(f1+f2)) bf16, invl = 1/rowsum ----------
// one wave per row; lane covers j in [lane*16, lane*16+16)
__global__ __launch_bounds__(256) void rowsum_P(const unsigned short* __restrict__ bm16,
                                                const float* __restrict__ f1,
                                                const float* __restrict__ f2,
                                                float* __restrict__ invl,
                                                unsigned short* __restrict__ P) {
  int row = blockIdx.x * 4 + (threadIdx.x >> 6);
  int lane = threadIdx.x & 63;
  int b = row >> 10;
  float f1v = f1[row];
  unsigned int bits = bm16[(size_t)row * 64 + lane];
  const float* f2p = f2 + (b << 10) + lane * 16;
  float4 v0 = ((const float4*)f2p)[0];
  float4 v1 = ((const float4*)f2p)[1];
  float4 v2 = ((const float4*)f2p)[2];
  float4 v3 = ((const float4*)f2p)[3];
  float fv[16] = {v0.x, v0.y, v0.z, v0.w, v1.x, v1.y, v1.z, v1.w,
                  v2.x, v2.y, v2.z, v2.w, v3.x, v3.y, v3.z, v3.w};
  float s = 0.f;
  alignas(16) unsigned short o[16];
  #pragma unroll
  for (int j = 0; j < 16; j++) {
    float p = 0.f;
    if ((bits >> j) & 1u) {
      float z = f1v + fv[j];
      z = z > 0.f ? z : ALPHA * z;
      p = __expf(z);
      s += p;
    }
    o[j] = f2b(p);
  }
  uint4* dst = (uint4*)(P + (size_t)row * 1024 + lane * 16);
  dst[0] = ((const uint4*)o)[0];
  dst[1] = ((const uint4*)o)[1];
  #pragma unroll
  for (int off = 32; off > 0; off >>= 1) s += __shfl_down(s, off);
  if (lane == 0) invl[row] = 1.0f / s;
}

// ---------- bf16 GEMM: C(MxN) = A(MxK) @ Bt(NxK)^T ----------
// 128x128 tile, BK=64, 4 waves each 64x64 (4x4 of 16x16x32 MFMA).
// XOR-swizzled LDS: logical (row, colblk cb of 8 shorts) stored at physical
// colblk = cb ^ (row&7). Row stride 128B => bank = f(colblk) only; the xor
// spreads a 16-lane fragment read over all 32 banks at 2/bank (free).
// global_load_lds width-16 staging: lane L -> row L/8, global colblk (L&7)^(L/8&7).
// EPI 1: bf16 out at [m][ocol+n]   (h -> hp right half)
// EPI 2: fp32 out, +bias, ELU      (final output)
// EPI 3: bf16 out, * scale[row]    (agg -> hp left half, scale = 1/l)
template <int EPI>
__global__ __launch_bounds__(256) void gemm_bt(
    const unsigned short* __restrict__ A, size_t aBS,
    const unsigned short* __restrict__ Bt, size_t bBS,
    int K,
    void* __restrict__ outp, size_t oBS, int ldo, int ocol,
    const float* __restrict__ scale,
    const float* __restrict__ bias) {
  __shared__ alignas(16) unsigned short As[128 * 64];
  __shared__ alignas(16) unsigned short Bs[128 * 64];
  const int tid = threadIdx.x;
  const int lane = tid & 63;
  const int w = tid >> 6;
  const int m0 = blockIdx.x * 128;
  const int n0 = blockIdx.y * 128;
  const int zb = blockIdx.z;
  const unsigned short* Ab = A + (size_t)zb * aBS;
  const unsigned short* Btb = Bt + (size_t)zb * bBS;

  f32x4 acc[4][4];
  #pragma unroll
  for (int i = 0; i < 4; i++)
    #pragma unroll
    for (int j = 0; j < 4; j++)
      #pragma unroll
      for (int r = 0; r < 4; r++) acc[i][j][r] = 0.f;

  // staging addresses: lane L covers 16B of row (w*32 + t*8 + L/8)
  const int lr = lane >> 3;                 // row within 8-row group
  const int lc = (lane & 7) ^ (lr & 7);     // swizzled global col-block
  const unsigned short* ag = Ab + (size_t)(m0 + w * 32 + lr) * K + lc * 8;
  const unsigned short* bg = Btb + (size_t)(n0 + w * 32 + lr) * K + lc * 8;
  unsigned short* asl = As + w * 32 * 64;
  unsigned short* bsl = Bs + w * 32 * 64;

  const int wm = (w & 1) * 64;
  const int wn = (w >> 1) * 64;
  const int row16 = lane & 15;
  const int quad = lane >> 4;
  const int sw = row16 & 7;                 // fragment-read swizzle

  for (int k0 = 0; k0 < K; k0 += 64) {
    __syncthreads();
    #pragma unroll
    for (int t = 0; t < 4; t++) {
      gl_lds16(ag + k0 + (size_t)(t * 8) * K, asl + t * 512);
      gl_lds16(bg + k0 + (size_t)(t * 8) * K, bsl + t * 512);
    }
    __syncthreads();
    short8 af[2][4], bf[2][4];
    #pragma unroll
    for (int s = 0; s < 2; s++) {
      #pragma unroll
      for (int i = 0; i < 4; i++) {
        af[s][i] = *(const short8*)(As + (wm + i * 16 + row16) * 64 + ((s * 4 + quad) ^ sw) * 8);
        bf[s][i] = *(const short8*)(Bs + (wn + i * 16 + row16) * 64 + ((s * 4 + quad) ^ sw) * 8);
      }
    }
    #pragma unroll
    for (int s = 0; s < 2; s++)
      #pragma unroll
      for (int am = 0; am < 4; am++)
        #pragma unroll
        for (int bn = 0; bn < 4; bn++)
          acc[am][bn] = __builtin_amdgcn_mfma_f32_16x16x32_bf16(af[s][am], bf[s][bn], acc[am][bn], 0, 0, 0);
  }

  // C/D layout: col = lane&15, row = (lane>>4)*4 + reg  [m89/m91-verified]
  const int col = lane & 15;
  const int r0 = quad * 4;
  #pragma unroll
  for (int am = 0; am < 4; am++) {
    #pragma unroll
    for (int bn = 0; bn < 4; bn++) {
      #pragma unroll
      for (int r = 0; r < 4; r++) {
        int m = m0 + wm + am * 16 + r0 + r;
        int n = n0 + wn + bn * 16 + col;
        float v = acc[am][bn][r];
        if (EPI == 3) v *= scale[zb * 1024 + m];
        if (EPI == 2) {
          v += bias[n];
          v = v > 0.f ? v : expm1f(v);   // ELU, alpha=1
          ((float*)outp)[(size_t)m * ldo + n] = v;
        } else {
          ((unsigned short*)outp)[(size_t)zb * oBS + (size_t)m * ldo + ocol + n] = f2b(v);
        }
      }
    }
  }
}

// ---------- launch ----------
extern "C" void kernel_launch(void* const* d_in, const int* in_sizes, int n_in,
                              void* d_out, int out_size, void* d_ws, size_t ws_size,
                              hipStream_t stream) {
  const float* x   = (const float*)d_in[0];  // (16,1024,1024)
  const int*   adj = (const int*)d_in[1];    // (16,1024,1024)
  const float* W   = (const float*)d_in[2];  // (1024,512)
  const float* a   = (const float*)d_in[3];  // (1024,1)
  const float* fcw = (const float*)d_in[4];  // (512,1024)  == Bt layout for GEMM3
  const float* fcb = (const float*)d_in[5];  // (512,)
  float* out = (float*)d_out;                // (16,1024,512) fp32
  char* ws = (char*)d_ws;

  // ws layout (~84.2 MiB; xb slot reused for P after GEMM1 consumes x)
  unsigned short* xb   = (unsigned short*)(ws);               // 32MB x_bf16 -> later P~
  unsigned short* hp   = (unsigned short*)(ws + 33554432);    // 32MB [agg | h] bf16 rows
  unsigned short* ht   = (unsigned short*)(ws + 67108864);    // 16MB h^T per batch
  unsigned short* Wt   = (unsigned short*)(ws + 83886080);    // 1MB
  unsigned short* fcwb = (unsigned short*)(ws + 84934656);    // 1MB
  float* f1            = (float*)(ws + 85983232);             // 64KB
  float* f2            = (float*)(ws + 86048768);             // 64KB
  float* invl          = (float*)(ws + 86114304);             // 64KB
  unsigned long long* bm = (unsigned long long*)(ws + 86179840); // 2MB
  unsigned short* P = xb;

  // 1: all input prep (pack/cvt/transpose)
  prep1<<<84480, 256, 0, stream>>>(adj, bm, x, xb, fcw, fcwb, W, Wt);

  // 2: GEMM1  h = x @ W  -> hp[:,512:1024]
  gemm_bt<1><<<dim3(128, 4, 1), 256, 0, stream>>>(xb, 0, Wt, 0, 1024,
                                                  hp, 0, 1024, 512, nullptr, nullptr);
  // 3: f1/f2 + h^T
  prep2<<<6144, 256, 0, stream>>>(hp, a, f1, f2, ht);
  // 4: P~ (unnormalized, bf16) + 1/rowsum
  rowsum_P<<<4096, 256, 0, stream>>>((const unsigned short*)bm, f1, f2, invl, P);

  // 5: GEMM2 (per batch): agg = (P~ @ h) * invl  -> hp[:,0:512]
  gemm_bt<3><<<dim3(8, 4, 16), 256, 0, stream>>>(P, 1024 * 1024, ht, 512 * 1024, 1024,
                                                 hp, 1024 * 1024, 1024, 0, invl, nullptr);
  // 6: GEMM3: out = elu([agg|h] @ fc_w^T + b)
  gemm_bt<2><<<dim3(128, 4, 1), 256, 0, stream>>>(hp, 0, fcwb, 0, 1024,
                                                  out, 0, 512, 0, nullptr, fcb);
}

// Round 3
// 266.146 us; speedup vs baseline: 1.2600x; 1.0379x over previous
//
#include <hip/hip_runtime.h>

#define ALPHA 0.2f

typedef __attribute__((ext_vector_type(8))) short short8;
typedef __attribute__((ext_vector_type(4))) float f32x4;

// ---------- helpers ----------
__device__ __forceinline__ unsigned short f2b(float f) {
  // round-to-nearest-even f32 -> bf16 bits
  unsigned int u; __builtin_memcpy(&u, &f, 4);
  unsigned int r = (u + 0x7FFFu + ((u >> 16) & 1u)) >> 16;
  return (unsigned short)r;
}
__device__ __forceinline__ float b2f(unsigned short v) {
  unsigned int u = ((unsigned int)v) << 16; float f; __builtin_memcpy(&f, &u, 4); return f;
}
__device__ __forceinline__ void gl_lds16(const unsigned short* g, unsigned short* l) {
  // async global->LDS, 16B/lane; LDS dst = wave-uniform base + lane*16
  __builtin_amdgcn_global_load_lds((__attribute__((address_space(1))) void*)g,
                                   (__attribute__((address_space(3))) void*)l, 16, 0, 0);
}

__device__ __forceinline__ void cvt8(const float* __restrict__ in, unsigned short* __restrict__ out,
                                     unsigned int gid) {
  // 8 fp32 -> 8 bf16, two independent float4 loads, one 16B store
  float4 v0 = ((const float4*)in)[gid * 2];
  float4 v1 = ((const float4*)in)[gid * 2 + 1];
  alignas(16) unsigned short o[8];
  o[0] = f2b(v0.x); o[1] = f2b(v0.y); o[2] = f2b(v0.z); o[3] = f2b(v0.w);
  o[4] = f2b(v1.x); o[5] = f2b(v1.y); o[6] = f2b(v1.z); o[7] = f2b(v1.w);
  ((uint4*)out)[gid] = *(const uint4*)o;
}

// ---------- prep1: pack_adj + cvt x->bf16 + cvt fcw->bf16 + transpose W ----------
// regions by blockIdx.x (wave-uniform branch):
//   [0,4096)       pack adj: 16 ints/thread via 4x int4 (64B ILP) -> ushort mask
//   [4096,12288)   x fp32 -> bf16, 8/thread (2x float4 -> uint4)
//   [12288,12544)  fcw fp32 -> bf16, 8/thread
//   [12544,12672)  W (1024x512) -> Wt bf16 (512x1024), 64x64 LDS tile transpose
__global__ __launch_bounds__(256) void prep1(const int* __restrict__ adj,
                                             unsigned short* __restrict__ bm16,
                                             const float* __restrict__ x,
                                             unsigned short* __restrict__ xb,
                                             const float* __restrict__ fcw,
                                             unsigned short* __restrict__ fcwb,
                                             const float* __restrict__ W,
                                             unsigned short* __restrict__ Wt) {
  __shared__ alignas(16) unsigned short tile[64][72];
  unsigned int bx = blockIdx.x;
  unsigned int tid = threadIdx.x;
  if (bx < 4096u) {
    unsigned int gid = bx * 256 + tid;          // 1M groups of 16 ints
    const int4* a4 = (const int4*)adj;
    int4 v0 = a4[gid * 4 + 0];
    int4 v1 = a4[gid * 4 + 1];
    int4 v2 = a4[gid * 4 + 2];
    int4 v3 = a4[gid * 4 + 3];
    unsigned int bits = 0;
    bits |= (v0.x > 0) << 0;  bits |= (v0.y > 0) << 1;  bits |= (v0.z > 0) << 2;  bits |= (v0.w > 0) << 3;
    bits |= (v1.x > 0) << 4;  bits |= (v1.y > 0) << 5;  bits |= (v1.z > 0) << 6;  bits |= (v1.w > 0) << 7;
    bits |= (v2.x > 0) << 8;  bits |= (v2.y > 0) << 9;  bits |= (v2.z > 0) << 10; bits |= (v2.w > 0) << 11;
    bits |= (v3.x > 0) << 12; bits |= (v3.y > 0) << 13; bits |= (v3.z > 0) << 14; bits |= (v3.w > 0) << 15;
    bm16[gid] = (unsigned short)bits;
  } else if (bx < 12288u) {
    cvt8(x, xb, (bx - 4096u) * 256 + tid);      // 2M threads x 8 elems
  } else if (bx < 12544u) {
    cvt8(fcw, fcwb, (bx - 12288u) * 256 + tid); // 64K threads x 8 elems
  } else {
    // W transpose: tile (k0..k0+64) x (n0..n0+64)
    unsigned int idx = bx - 12544u;             // 128 blocks: 16 k-tiles x 8 n-tiles
    unsigned int k0 = (idx >> 3) * 64, n0 = (idx & 7) * 64;
    #pragma unroll
    for (int p = 0; p < 4; p++) {
      int r = p * 16 + (tid >> 4);
      int c = (tid & 15) * 4;
      float4 v = *(const float4*)(W + (size_t)(k0 + r) * 512 + n0 + c);
      tile[r][c] = f2b(v.x); tile[r][c + 1] = f2b(v.y);
      tile[r][c + 2] = f2b(v.z); tile[r][c + 3] = f2b(v.w);
    }
    __syncthreads();
    int f = tid >> 2;
    int ic = (tid & 3) * 16;
    alignas(16) unsigned short buf[16];
    #pragma unroll
    for (int k = 0; k < 16; k++) buf[k] = tile[ic + k][f];
    uint4* dst = (uint4*)(Wt + (size_t)(n0 + f) * 1024 + k0 + ic);
    dst[0] = ((const uint4*)buf)[0];
    dst[1] = ((const uint4*)buf)[1];
  }
}

// ---------- prep2: f1f2 + transpose_h (both depend only on GEMM1) ----------
__global__ __launch_bounds__(256) void prep2(const unsigned short* __restrict__ hp,
                                             const float* __restrict__ a,
                                             float* __restrict__ f1, float* __restrict__ f2,
                                             unsigned short* __restrict__ ht) {
  __shared__ alignas(16) unsigned short tile[64][72];
  int bx = blockIdx.x;
  int tid = threadIdx.x;
  if (bx < 4096) {
    // f1[m]=h[m]·a1, f2[m]=h[m]·a2 ; one wave per row
    int row = bx * 4 + (tid >> 6);
    int lane = tid & 63;
    const unsigned short* hrow = hp + (size_t)row * 1024 + 512;
    uint4 raw = *(const uint4*)(hrow + lane * 8);
    alignas(16) unsigned short hv[8]; __builtin_memcpy(hv, &raw, 16);
    float s1 = 0.f, s2 = 0.f;
    #pragma unroll
    for (int j = 0; j < 8; j++) {
      float hf = b2f(hv[j]);
      s1 += hf * a[lane * 8 + j];
      s2 += hf * a[512 + lane * 8 + j];
    }
    #pragma unroll
    for (int o = 32; o > 0; o >>= 1) { s1 += __shfl_down(s1, o); s2 += __shfl_down(s2, o); }
    if (lane == 0) { f1[row] = s1; f2[row] = s2; }
  } else {
    // hp h-half -> ht[b][f][i] (B^T layout for attention GEMM), 64x64 LDS tile transpose
    int idx = bx - 4096;                 // 2048 blocks: (16 b) x (8 f0) x (16 i0)
    int b = idx >> 7;
    int f0 = ((idx >> 4) & 7) * 64;
    int i0 = (idx & 15) * 64;
    #pragma unroll
    for (int p = 0; p < 2; p++) {
      int r = p * 32 + (tid >> 3);
      int c = (tid & 7) * 8;
      uint4 v = *(const uint4*)(hp + (size_t)(b * 1024 + i0 + r) * 1024 + 512 + f0 + c);
      *(uint4*)(&tile[r][c]) = v;
    }
    __syncthreads();
    int f = tid >> 2;
    int ic = (tid & 3) * 16;
    alignas(16) unsigned short buf[16];
    #pragma unroll
    for (int k = 0; k < 16; k++) buf[k] = tile[ic + k][f];
    uint4* dst = (uint4*)(ht + (size_t)(b * 512 + f0 + f) * 1024 + i0 + ic);
    dst[0] = ((const uint4*)buf)[0];
    dst[1] = ((const uint4*)buf)[1];
  }
}

// ---------- rowsum + P in one pass: P~ = mask*exp(lrelu(f1+f2)) bf16, invl = 1/rowsum ----------
// one wave per row; lane covers j in [lane*16, lane*16+16)
__global__ __launch_bounds__(256) void rowsum_P(const unsigned short* __restrict__ bm16,
                                                const float* __restrict__ f1,
                                                const float* __restrict__ f2,
                                                float* __restrict__ invl,
                                                unsigned short* __restrict__ P) {
  int row = blockIdx.x * 4 + (threadIdx.x >> 6);
  int lane = threadIdx.x & 63;
  int b = row >> 10;
  float f1v = f1[row];
  unsigned int bits = bm16[(size_t)row * 64 + lane];
  const float* f2p = f2 + (b << 10) + lane * 16;
  float4 v0 = ((const float4*)f2p)[0];
  float4 v1 = ((const float4*)f2p)[1];
  float4 v2 = ((const float4*)f2p)[2];
  float4 v3 = ((const float4*)f2p)[3];
  float fv[16] = {v0.x, v0.y, v0.z, v0.w, v1.x, v1.y, v1.z, v1.w,
                  v2.x, v2.y, v2.z, v2.w, v3.x, v3.y, v3.z, v3.w};
  float s = 0.f;
  alignas(16) unsigned short o[16];
  #pragma unroll
  for (int j = 0; j < 16; j++) {
    float p = 0.f;
    if ((bits >> j) & 1u) {
      float z = f1v + fv[j];
      z = z > 0.f ? z : ALPHA * z;
      p = __expf(z);
      s += p;
    }
    o[j] = f2b(p);
  }
  uint4* dst = (uint4*)(P + (size_t)row * 1024 + lane * 16);
  dst[0] = ((const uint4*)o)[0];
  dst[1] = ((const uint4*)o)[1];
  #pragma unroll
  for (int off = 32; off > 0; off >>= 1) s += __shfl_down(s, off);
  if (lane == 0) invl[row] = 1.0f / s;
}

// ---------- bf16 GEMM: C(MxN) = A(MxK) @ Bt(NxK)^T ----------
// 128x128 tile, BK=64, 4 waves each 64x64 (4x4 of 16x16x32 MFMA).
// XOR-swizzled LDS: logical (row, colblk cb of 8 shorts) stored at physical
// colblk = cb ^ (row&7). Row stride 128B => bank = f(colblk) only; the xor
// spreads a 16-lane fragment read over all 32 banks at 2/bank (free).
// global_load_lds width-16 staging: lane L -> row L/8, global colblk (L&7)^(L/8&7).
// EPI 1: bf16 out at [m][ocol+n]   (h -> hp right half)
// EPI 2: fp32 out, +bias, ELU      (final output)
// EPI 3: bf16 out, * scale[row]    (agg -> hp left half, scale = 1/l)
template <int EPI>
__global__ __launch_bounds__(256) void gemm_bt(
    const unsigned short* __restrict__ A, size_t aBS,
    const unsigned short* __restrict__ Bt, size_t bBS,
    int K,
    void* __restrict__ outp, size_t oBS, int ldo, int ocol,
    const float* __restrict__ scale,
    const float* __restrict__ bias) {
  __shared__ alignas(16) unsigned short As[128 * 64];
  __shared__ alignas(16) unsigned short Bs[128 * 64];
  const int tid = threadIdx.x;
  const int lane = tid & 63;
  const int w = tid >> 6;
  const int m0 = blockIdx.x * 128;
  const int n0 = blockIdx.y * 128;
  const int zb = blockIdx.z;
  const unsigned short* Ab = A + (size_t)zb * aBS;
  const unsigned short* Btb = Bt + (size_t)zb * bBS;

  f32x4 acc[4][4];
  #pragma unroll
  for (int i = 0; i < 4; i++)
    #pragma unroll
    for (int j = 0; j < 4; j++)
      #pragma unroll
      for (int r = 0; r < 4; r++) acc[i][j][r] = 0.f;

  // staging addresses: lane L covers 16B of row (w*32 + t*8 + L/8)
  const int lr = lane >> 3;                 // row within 8-row group
  const int lc = (lane & 7) ^ (lr & 7);     // swizzled global col-block
  const unsigned short* ag = Ab + (size_t)(m0 + w * 32 + lr) * K + lc * 8;
  const unsigned short* bg = Btb + (size_t)(n0 + w * 32 + lr) * K + lc * 8;
  unsigned short* asl = As + w * 32 * 64;
  unsigned short* bsl = Bs + w * 32 * 64;

  const int wm = (w & 1) * 64;
  const int wn = (w >> 1) * 64;
  const int row16 = lane & 15;
  const int quad = lane >> 4;
  const int sw = row16 & 7;                 // fragment-read swizzle

  for (int k0 = 0; k0 < K; k0 += 64) {
    __syncthreads();
    #pragma unroll
    for (int t = 0; t < 4; t++) {
      gl_lds16(ag + k0 + (size_t)(t * 8) * K, asl + t * 512);
      gl_lds16(bg + k0 + (size_t)(t * 8) * K, bsl + t * 512);
    }
    __syncthreads();
    short8 af[2][4], bf[2][4];
    #pragma unroll
    for (int s = 0; s < 2; s++) {
      #pragma unroll
      for (int i = 0; i < 4; i++) {
        af[s][i] = *(const short8*)(As + (wm + i * 16 + row16) * 64 + ((s * 4 + quad) ^ sw) * 8);
        bf[s][i] = *(const short8*)(Bs + (wn + i * 16 + row16) * 64 + ((s * 4 + quad) ^ sw) * 8);
      }
    }
    #pragma unroll
    for (int s = 0; s < 2; s++)
      #pragma unroll
      for (int am = 0; am < 4; am++)
        #pragma unroll
        for (int bn = 0; bn < 4; bn++)
          acc[am][bn] = __builtin_amdgcn_mfma_f32_16x16x32_bf16(af[s][am], bf[s][bn], acc[am][bn], 0, 0, 0);
  }

  // C/D layout: col = lane&15, row = (lane>>4)*4 + reg  [m89/m91-verified]
  const int col = lane & 15;
  const int r0 = quad * 4;
  #pragma unroll
  for (int am = 0; am < 4; am++) {
    #pragma unroll
    for (int bn = 0; bn < 4; bn++) {
      #pragma unroll
      for (int r = 0; r < 4; r++) {
        int m = m0 + wm + am * 16 + r0 + r;
        int n = n0 + wn + bn * 16 + col;
        float v = acc[am][bn][r];
        if (EPI == 3) v *= scale[zb * 1024 + m];
        if (EPI == 2) {
          v += bias[n];
          v = v > 0.f ? v : expm1f(v);   // ELU, alpha=1
          ((float*)outp)[(size_t)m * ldo + n] = v;
        } else {
          ((unsigned short*)outp)[(size_t)zb * oBS + (size_t)m * ldo + ocol + n] = f2b(v);
        }
      }
    }
  }
}

// ---------- launch ----------
extern "C" void kernel_launch(void* const* d_in, const int* in_sizes, int n_in,
                              void* d_out, int out_size, void* d_ws, size_t ws_size,
                              hipStream_t stream) {
  const float* x   = (const float*)d_in[0];  // (16,1024,1024)
  const int*   adj = (const int*)d_in[1];    // (16,1024,1024)
  const float* W   = (const float*)d_in[2];  // (1024,512)
  const float* a   = (const float*)d_in[3];  // (1024,1)
  const float* fcw = (const float*)d_in[4];  // (512,1024)  == Bt layout for GEMM3
  const float* fcb = (const float*)d_in[5];  // (512,)
  float* out = (float*)d_out;                // (16,1024,512) fp32
  char* ws = (char*)d_ws;

  // ws layout (~84.2 MiB; xb slot reused for P after GEMM1 consumes x)
  unsigned short* xb   = (unsigned short*)(ws);               // 32MB x_bf16 -> later P~
  unsigned short* hp   = (unsigned short*)(ws + 33554432);    // 32MB [agg | h] bf16 rows
  unsigned short* ht   = (unsigned short*)(ws + 67108864);    // 16MB h^T per batch
  unsigned short* Wt   = (unsigned short*)(ws + 83886080);    // 1MB
  unsigned short* fcwb = (unsigned short*)(ws + 84934656);    // 1MB
  float* f1            = (float*)(ws + 85983232);             // 64KB
  float* f2            = (float*)(ws + 86048768);             // 64KB
  float* invl          = (float*)(ws + 86114304);             // 64KB
  unsigned short* bm   = (unsigned short*)(ws + 86179840);    // 2MB bitmask
  unsigned short* P = xb;

  // 1: all input prep (pack/cvt/transpose)
  prep1<<<12672, 256, 0, stream>>>(adj, bm, x, xb, fcw, fcwb, W, Wt);

  // 2: GEMM1  h = x @ W  -> hp[:,512:1024]
  gemm_bt<1><<<dim3(128, 4, 1), 256, 0, stream>>>(xb, 0, Wt, 0, 1024,
                                                  hp, 0, 1024, 512, nullptr, nullptr);
  // 3: f1/f2 + h^T
  prep2<<<6144, 256, 0, stream>>>(hp, a, f1, f2, ht);
  // 4: P~ (unnormalized, bf16) + 1/rowsum
  rowsum_P<<<4096, 256, 0, stream>>>(bm, f1, f2, invl, P);

  // 5: GEMM2 (per batch): agg = (P~ @ h) * invl  -> hp[:,0:512]
  gemm_bt<3><<<dim3(8, 4, 16), 256, 0, stream>>>(P, 1024 * 1024, ht, 512 * 1024, 1024,
                                                 hp, 1024 * 1024, 1024, 0, invl, nullptr);
  // 6: GEMM3: out = elu([agg|h] @ fc_w^T + b)
  gemm_bt<2><<<dim3(128, 4, 1), 256, 0, stream>>>(hp, 0, fcwb, 0, 1024,
                                                  out, 0, 512, 0, nullptr, fcb);
}